// Round 8
// baseline (83.938 us; speedup 1.0000x reference)
//
#include <hip/hip_runtime.h>
#include <hip/hip_bf16.h>
#include <math.h>

#define B_ 64
#define T_ 512
#define D_ 768
#define H_ 96
#define M_ (B_*T_)   // 32768 rows

typedef __attribute__((ext_vector_type(8))) short short8;
typedef __attribute__((ext_vector_type(4))) float f32x4;

__device__ __forceinline__ short f2bf(float f) {
  unsigned u = __float_as_uint(f);
  unsigned r = (u + 0x7FFFu + ((u >> 16) & 1u)) >> 16;   // RTNE
  return (short)r;
}

// ---------------------------------------------------------------------------
// Kernel 0: W -> bf16, transposed to [n][k] (n = mi*96+cc, 288 x 768).
// ---------------------------------------------------------------------------
__global__ __launch_bounds__(256) void wt_kernel(
    const float* __restrict__ Wq, const float* __restrict__ Wk,
    const float* __restrict__ Wv, short* __restrict__ wt)
{
  int id = blockIdx.x * 256 + threadIdx.x;     // 3*96*768 = 221184
  if (id >= 3*H_*D_) return;
  int n = id % 288;
  int k = id / 288;
  int mi = n / 96, cc = n % 96;
  const float* Wm = (mi == 0) ? Wq : ((mi == 1) ? Wk : Wv);
  wt[(size_t)n * D_ + k] = f2bf(Wm[(size_t)k * H_ + cc]);
}

// ---------------------------------------------------------------------------
// Kernel 1: QKV projection via MFMA bf16 (fp32 accumulate), bf16 outputs.
// q,k: bf16 [M][96] row-major.  v: bf16 [B][96][T] (transposed per batch).
// BK=32, ASTR=36 -> LDS 59,904 B -> 2 blocks/CU (2 waves/SIMD) for latency
// hiding (round-6 diagnosis: 119 KB LDS gave 1 wave/SIMD, 58 us latency-bound).
// ---------------------------------------------------------------------------
#define BMP 128
#define BKP 32
#define ASTR 36

__global__ __launch_bounds__(256) void qkv_mfma_kernel(
    const float* __restrict__ x, const short* __restrict__ wt,
    short* __restrict__ qb, short* __restrict__ kb, short* __restrict__ vtp)
{
  __shared__ short as[2][BMP][ASTR];   // 18,432 B
  __shared__ short bs[2][288][ASTR];   // 41,472 B   (total 59,904 B)

  const int t    = threadIdx.x;
  const int row0 = blockIdx.x * BMP;
  const int lane = t & 63;
  const int w    = t >> 6;
  const int wr   = w >> 1;
  const int wc   = w & 1;
  const int l15  = lane & 15;
  const int l4   = lane >> 4;

  auto stage = [&](int buf, int k0) {
    // x tile: 128 x 32 fp32 -> bf16.  512 chunks of 8; 2 per thread.
    #pragma unroll
    for (int i = 0; i < 2; ++i) {
      int id = t + i * 256;
      int m = id >> 2, k8 = id & 3;
      const float* src = x + (size_t)(row0 + m) * D_ + k0 + k8 * 8;
      float4 f0 = *reinterpret_cast<const float4*>(src);
      float4 f1 = *reinterpret_cast<const float4*>(src + 4);
      short8 v;
      v[0] = f2bf(f0.x); v[1] = f2bf(f0.y); v[2] = f2bf(f0.z); v[3] = f2bf(f0.w);
      v[4] = f2bf(f1.x); v[5] = f2bf(f1.y); v[6] = f2bf(f1.z); v[7] = f2bf(f1.w);
      *reinterpret_cast<short8*>(&as[buf][m][k8 * 8]) = v;
    }
    // W tile: 288 x 32 bf16.  1152 chunks of 8; 4 per thread + waves 0-1 a 5th.
    #pragma unroll
    for (int i = 0; i < 4; ++i) {
      int id = t + i * 256;
      int n = id >> 2, k8 = id & 3;
      short8 v = *reinterpret_cast<const short8*>(wt + (size_t)n * D_ + k0 + k8 * 8);
      *reinterpret_cast<short8*>(&bs[buf][n][k8 * 8]) = v;
    }
    if (t < 128) {                     // wave-uniform tail (ids 1024..1151)
      int id = t + 1024;
      int n = id >> 2, k8 = id & 3;
      short8 v = *reinterpret_cast<const short8*>(wt + (size_t)n * D_ + k0 + k8 * 8);
      *reinterpret_cast<short8*>(&bs[buf][n][k8 * 8]) = v;
    }
  };

  f32x4 acc[4][9];
  #pragma unroll
  for (int ri = 0; ri < 4; ++ri)
    #pragma unroll
    for (int ci = 0; ci < 9; ++ci) acc[ri][ci] = (f32x4){0.f, 0.f, 0.f, 0.f};

  stage(0, 0);
  __syncthreads();

  for (int ks = 0; ks < D_ / BKP; ++ks) {       // 24 steps
    int buf = ks & 1;
    if (ks + 1 < D_ / BKP) stage(buf ^ 1, (ks + 1) * BKP);

    short8 a[4];
    #pragma unroll
    for (int ri = 0; ri < 4; ++ri) {
      int m = wr * 64 + ri * 16 + l15;
      a[ri] = *reinterpret_cast<const short8*>(&as[buf][m][l4 * 8]);
    }
    #pragma unroll
    for (int ci = 0; ci < 9; ++ci) {
      int n = wc * 144 + ci * 16 + l15;
      short8 bfrag = *reinterpret_cast<const short8*>(&bs[buf][n][l4 * 8]);
      #pragma unroll
      for (int ri = 0; ri < 4; ++ri)
        acc[ri][ci] = __builtin_amdgcn_mfma_f32_16x16x32_bf16(
            a[ri], bfrag, acc[ri][ci], 0, 0, 0);
    }
    __syncthreads();
  }

  // epilogue: C frag (ri,ci): row(token) = row0+wr*64+ri*16+l4*4+reg,
  //                           col(n)    = wc*144+ci*16+l15
  #pragma unroll
  for (int ci = 0; ci < 9; ++ci) {
    int ncol = wc * 144 + ci * 16;
    int mi   = ncol / 96;          // wave-uniform
    int cc   = ncol % 96 + l15;
    #pragma unroll
    for (int ri = 0; ri < 4; ++ri) {
      int rbase = row0 + wr * 64 + ri * 16 + l4 * 4;
      if (mi == 2) {
        int bb = rbase / T_, tl = rbase % T_;     // 4 tokens same batch (4 | T)
        short4 pk;
        pk.x = f2bf(acc[ri][ci][0]); pk.y = f2bf(acc[ri][ci][1]);
        pk.z = f2bf(acc[ri][ci][2]); pk.w = f2bf(acc[ri][ci][3]);
        *reinterpret_cast<short4*>(vtp + ((size_t)bb * H_ + cc) * T_ + tl) = pk;
      } else {
        short* Om = (mi == 0) ? qb : kb;
        #pragma unroll
        for (int reg = 0; reg < 4; ++reg)
          Om[(size_t)(rbase + reg) * H_ + cc] = f2bf(acc[ri][ci][reg]);
      }
    }
  }
}

// ---------------------------------------------------------------------------
// Kernel 2: causal flash attention via MFMA bf16 (unchanged from round 6).
// ---------------------------------------------------------------------------
#define QB 32
#define KVB 32
#define KSTR 104
#define VSTR 40
#define PSTR 40

__global__ __launch_bounds__(128) void attn_mfma_kernel(
    const short* __restrict__ qb, const short* __restrict__ kb,
    const short* __restrict__ vtp, float* __restrict__ out)
{
  __shared__ short ks[KVB][KSTR];     // 6656 B
  __shared__ short vs[H_][VSTR];      // 7680 B
  __shared__ short ps[2][16][PSTR];   // 2560 B

  const int t    = threadIdx.x;
  const int lane = t & 63;
  const int w    = t >> 6;            // 0..1
  const int l15  = lane & 15;
  const int l4   = lane >> 4;
  const int qi   = 15 - blockIdx.x;   // heavy blocks first
  const int b    = blockIdx.y;
  const int q0   = qi * QB;

  short8 qf[3];
  {
    const short* qbase = qb + ((size_t)(b * T_) + q0 + w * 16 + l15) * H_;
    #pragma unroll
    for (int f = 0; f < 3; ++f)
      qf[f] = *reinterpret_cast<const short8*>(qbase + f * 32 + l4 * 8);
  }

  f32x4 acc[6];
  #pragma unroll
  for (int c = 0; c < 6; ++c) acc[c] = (f32x4){0.f, 0.f, 0.f, 0.f};
  float m_r[4] = {-INFINITY, -INFINITY, -INFINITY, -INFINITY};
  float l_r[4] = {0.f, 0.f, 0.f, 0.f};
  const float scale = 0.10206207261596576f;   // 1/sqrt(96)

  const int jmax = q0 + QB;
  for (int j0 = 0; j0 < jmax; j0 += KVB) {
    __syncthreads();
    {  // stage K tile: 32 rows x 96 bf16
      int row = t >> 2, seg = t & 3;
      const short* src = kb + ((size_t)(b * T_) + j0 + row) * H_ + seg * 24;
      short* dst = &ks[row][seg * 24];
      *reinterpret_cast<short8*>(dst)      = *reinterpret_cast<const short8*>(src);
      *reinterpret_cast<short8*>(dst + 8)  = *reinterpret_cast<const short8*>(src + 8);
      *reinterpret_cast<short8*>(dst + 16) = *reinterpret_cast<const short8*>(src + 16);
    }
    {  // stage V tile: 96 h x 32 keys (pre-transposed in global)
      #pragma unroll
      for (int i = 0; i < 3; ++i) {
        int c = t + i * 128;
        int h = c >> 2, k8 = c & 3;
        *reinterpret_cast<short8*>(&vs[h][k8 * 8]) =
            *reinterpret_cast<const short8*>(vtp + ((size_t)b * H_ + h) * T_ + j0 + k8 * 8);
      }
    }
    __syncthreads();

    f32x4 sfr[2];
    sfr[0] = (f32x4){0.f,0.f,0.f,0.f};
    sfr[1] = (f32x4){0.f,0.f,0.f,0.f};
    #pragma unroll
    for (int ct = 0; ct < 2; ++ct)
      #pragma unroll
      for (int f = 0; f < 3; ++f) {
        short8 kf = *reinterpret_cast<const short8*>(&ks[ct * 16 + l15][f * 32 + l4 * 8]);
        sfr[ct] = __builtin_amdgcn_mfma_f32_16x16x32_bf16(qf[f], kf, sfr[ct], 0, 0, 0);
      }

    const int qrow = q0 + w * 16 + l4 * 4;   // +reg
    float p0[4], p1[4], fsc[4];
    #pragma unroll
    for (int reg = 0; reg < 4; ++reg) {
      float s0 = sfr[0][reg] * scale;
      float s1 = sfr[1][reg] * scale;
      if (j0 + l15      > qrow + reg) s0 = -INFINITY;
      if (j0 + l15 + 16 > qrow + reg) s1 = -INFINITY;
      float tm = fmaxf(s0, s1);
      #pragma unroll
      for (int o = 1; o < 16; o <<= 1) tm = fmaxf(tm, __shfl_xor(tm, o));
      float Mnew = fmaxf(m_r[reg], tm);
      p0[reg] = __expf(s0 - Mnew);
      p1[reg] = __expf(s1 - Mnew);
      float psum = p0[reg] + p1[reg];
      #pragma unroll
      for (int o = 1; o < 16; o <<= 1) psum += __shfl_xor(psum, o);
      fsc[reg] = __expf(m_r[reg] - Mnew);
      m_r[reg] = Mnew;
      l_r[reg] = l_r[reg] * fsc[reg] + psum;
    }
    #pragma unroll
    for (int c = 0; c < 6; ++c)
      #pragma unroll
      for (int reg = 0; reg < 4; ++reg) acc[c][reg] *= fsc[reg];

    #pragma unroll
    for (int reg = 0; reg < 4; ++reg) {
      ps[w][l4 * 4 + reg][l15]      = f2bf(p0[reg]);
      ps[w][l4 * 4 + reg][l15 + 16] = f2bf(p1[reg]);
    }
    short8 pa = *reinterpret_cast<const short8*>(&ps[w][l15][l4 * 8]);

    #pragma unroll
    for (int c = 0; c < 6; ++c) {
      short8 vf = *reinterpret_cast<const short8*>(&vs[c * 16 + l15][l4 * 8]);
      acc[c] = __builtin_amdgcn_mfma_f32_16x16x32_bf16(pa, vf, acc[c], 0, 0, 0);
    }
  }

  float inv[4];
  #pragma unroll
  for (int reg = 0; reg < 4; ++reg) inv[reg] = 1.f / l_r[reg];
  #pragma unroll
  for (int c = 0; c < 6; ++c) {
    #pragma unroll
    for (int reg = 0; reg < 4; ++reg) {
      size_t row = (size_t)(b * T_) + q0 + w * 16 + l4 * 4 + reg;
      out[row * H_ + c * 16 + l15] = acc[c][reg] * inv[reg];
    }
  }
}

extern "C" void kernel_launch(void* const* d_in, const int* in_sizes, int n_in,
                              void* d_out, int out_size, void* d_ws, size_t ws_size,
                              hipStream_t stream) {
  const float* x  = (const float*)d_in[0];
  const float* Wq = (const float*)d_in[1];
  const float* Wk = (const float*)d_in[2];
  const float* Wv = (const float*)d_in[3];

  short* wt  = (short*)d_ws;                               // 442,368 B
  short* qb  = (short*)((char*)d_ws + 524288);             // 6,291,456 B
  short* kb  = qb + (size_t)M_ * H_;
  short* vtp = kb + (size_t)M_ * H_;                       // [B][96][T]
  float* outp = (float*)d_out;

  hipLaunchKernelGGL(wt_kernel, dim3((3*H_*D_ + 255)/256), dim3(256), 0, stream,
                     Wq, Wk, Wv, wt);
  hipLaunchKernelGGL(qkv_mfma_kernel, dim3(M_/BMP), dim3(256), 0, stream,
                     x, wt, qb, kb, vtp);
  hipLaunchKernelGGL(attn_mfma_kernel, dim3(T_/QB, B_), dim3(128), 0, stream,
                     qb, kb, vtp, outp);
}

// Round 9
// 80.794 us; speedup vs baseline: 1.0389x; 1.0389x over previous
//
#include <hip/hip_runtime.h>
#include <hip/hip_bf16.h>
#include <math.h>

#define B_ 64
#define T_ 512
#define D_ 768
#define H_ 96
#define M_ (B_*T_)   // 32768 rows

typedef __attribute__((ext_vector_type(8))) short short8;
typedef __attribute__((ext_vector_type(4))) float f32x4;

__device__ __forceinline__ short f2bf(float f) {
  unsigned u = __float_as_uint(f);
  unsigned r = (u + 0x7FFFu + ((u >> 16) & 1u)) >> 16;   // RTNE
  return (short)r;
}

// ---------------------------------------------------------------------------
// Kernel 0: W -> bf16, transposed to [n][k] (n = mi*96+cc, 288 x 768).
// ---------------------------------------------------------------------------
__global__ __launch_bounds__(256) void wt_kernel(
    const float* __restrict__ Wq, const float* __restrict__ Wk,
    const float* __restrict__ Wv, short* __restrict__ wt)
{
  int id = blockIdx.x * 256 + threadIdx.x;     // 3*96*768 = 221184
  if (id >= 3*H_*D_) return;
  int n = id % 288;
  int k = id / 288;
  int mi = n / 96, cc = n % 96;
  const float* Wm = (mi == 0) ? Wq : ((mi == 1) ? Wk : Wv);
  wt[(size_t)n * D_ + k] = f2bf(Wm[(size_t)k * H_ + cc]);
}

// ---------------------------------------------------------------------------
// Kernel 1: QKV projection via MFMA bf16 (fp32 accumulate), bf16 outputs.
// q,k: bf16 [M][96] row-major.  v: bf16 [B][96][T] (transposed per batch).
// BMP=64 -> grid 512 = 2 blocks/CU (round-8 diagnosis: BMP=128 gave grid 256
// = 1 block/CU, occupancy grid-limited at 10%, 58 us latency-bound).
// BK=32, ASTR=36 -> LDS 50,688 B, fits 2 blocks/CU.
// ---------------------------------------------------------------------------
#define BMP 64
#define BKP 32
#define ASTR 36

__global__ __launch_bounds__(256) void qkv_mfma_kernel(
    const float* __restrict__ x, const short* __restrict__ wt,
    short* __restrict__ qb, short* __restrict__ kb, short* __restrict__ vtp)
{
  __shared__ short as[2][BMP][ASTR];   //  9,216 B
  __shared__ short bs[2][288][ASTR];   // 41,472 B   (total 50,688 B)

  const int t    = threadIdx.x;
  const int row0 = blockIdx.x * BMP;
  const int lane = t & 63;
  const int w    = t >> 6;
  const int wr   = w >> 1;      // row half (rows wr*32 .. +32)
  const int wc   = w & 1;       // col half (cols wc*144 .. +144)
  const int l15  = lane & 15;
  const int l4   = lane >> 4;

  auto stage = [&](int buf, int k0) {
    // x tile: 64 x 32 fp32 -> bf16.  256 chunks of 8; 1 per thread.
    {
      int m = t >> 2, k8 = t & 3;
      const float* src = x + (size_t)(row0 + m) * D_ + k0 + k8 * 8;
      float4 f0 = *reinterpret_cast<const float4*>(src);
      float4 f1 = *reinterpret_cast<const float4*>(src + 4);
      short8 v;
      v[0] = f2bf(f0.x); v[1] = f2bf(f0.y); v[2] = f2bf(f0.z); v[3] = f2bf(f0.w);
      v[4] = f2bf(f1.x); v[5] = f2bf(f1.y); v[6] = f2bf(f1.z); v[7] = f2bf(f1.w);
      *reinterpret_cast<short8*>(&as[buf][m][k8 * 8]) = v;
    }
    // W tile: 288 x 32 bf16.  1152 chunks of 8; 4 per thread + waves 0-1 a 5th.
    #pragma unroll
    for (int i = 0; i < 4; ++i) {
      int id = t + i * 256;
      int n = id >> 2, k8 = id & 3;
      short8 v = *reinterpret_cast<const short8*>(wt + (size_t)n * D_ + k0 + k8 * 8);
      *reinterpret_cast<short8*>(&bs[buf][n][k8 * 8]) = v;
    }
    if (t < 128) {                     // ids 1024..1151
      int id = t + 1024;
      int n = id >> 2, k8 = id & 3;
      short8 v = *reinterpret_cast<const short8*>(wt + (size_t)n * D_ + k0 + k8 * 8);
      *reinterpret_cast<short8*>(&bs[buf][n][k8 * 8]) = v;
    }
  };

  f32x4 acc[2][9];
  #pragma unroll
  for (int ri = 0; ri < 2; ++ri)
    #pragma unroll
    for (int ci = 0; ci < 9; ++ci) acc[ri][ci] = (f32x4){0.f, 0.f, 0.f, 0.f};

  stage(0, 0);
  __syncthreads();

  for (int ks = 0; ks < D_ / BKP; ++ks) {       // 24 steps
    int buf = ks & 1;
    if (ks + 1 < D_ / BKP) stage(buf ^ 1, (ks + 1) * BKP);

    short8 a[2];
    #pragma unroll
    for (int ri = 0; ri < 2; ++ri) {
      int m = wr * 32 + ri * 16 + l15;
      a[ri] = *reinterpret_cast<const short8*>(&as[buf][m][l4 * 8]);
    }
    #pragma unroll
    for (int ci = 0; ci < 9; ++ci) {
      int n = wc * 144 + ci * 16 + l15;
      short8 bfrag = *reinterpret_cast<const short8*>(&bs[buf][n][l4 * 8]);
      #pragma unroll
      for (int ri = 0; ri < 2; ++ri)
        acc[ri][ci] = __builtin_amdgcn_mfma_f32_16x16x32_bf16(
            a[ri], bfrag, acc[ri][ci], 0, 0, 0);
    }
    __syncthreads();
  }

  // epilogue: C frag (ri,ci): row(token) = row0+wr*32+ri*16+l4*4+reg,
  //                           col(n)    = wc*144+ci*16+l15
  #pragma unroll
  for (int ci = 0; ci < 9; ++ci) {
    int ncol = wc * 144 + ci * 16;
    int mi   = ncol / 96;          // wave-uniform
    int cc   = ncol % 96 + l15;
    #pragma unroll
    for (int ri = 0; ri < 2; ++ri) {
      int rbase = row0 + wr * 32 + ri * 16 + l4 * 4;
      if (mi == 2) {
        int bb = rbase / T_, tl = rbase % T_;     // 4 tokens same batch (4 | T)
        short4 pk;
        pk.x = f2bf(acc[ri][ci][0]); pk.y = f2bf(acc[ri][ci][1]);
        pk.z = f2bf(acc[ri][ci][2]); pk.w = f2bf(acc[ri][ci][3]);
        *reinterpret_cast<short4*>(vtp + ((size_t)bb * H_ + cc) * T_ + tl) = pk;
      } else {
        short* Om = (mi == 0) ? qb : kb;
        #pragma unroll
        for (int reg = 0; reg < 4; ++reg)
          Om[(size_t)(rbase + reg) * H_ + cc] = f2bf(acc[ri][ci][reg]);
      }
    }
  }
}

// ---------------------------------------------------------------------------
// Kernel 2: causal flash attention via MFMA bf16 (unchanged from round 6).
// ---------------------------------------------------------------------------
#define QB 32
#define KVB 32
#define KSTR 104
#define VSTR 40
#define PSTR 40

__global__ __launch_bounds__(128) void attn_mfma_kernel(
    const short* __restrict__ qb, const short* __restrict__ kb,
    const short* __restrict__ vtp, float* __restrict__ out)
{
  __shared__ short ks[KVB][KSTR];     // 6656 B
  __shared__ short vs[H_][VSTR];      // 7680 B
  __shared__ short ps[2][16][PSTR];   // 2560 B

  const int t    = threadIdx.x;
  const int lane = t & 63;
  const int w    = t >> 6;            // 0..1
  const int l15  = lane & 15;
  const int l4   = lane >> 4;
  const int qi   = 15 - blockIdx.x;   // heavy blocks first
  const int b    = blockIdx.y;
  const int q0   = qi * QB;

  short8 qf[3];
  {
    const short* qbase = qb + ((size_t)(b * T_) + q0 + w * 16 + l15) * H_;
    #pragma unroll
    for (int f = 0; f < 3; ++f)
      qf[f] = *reinterpret_cast<const short8*>(qbase + f * 32 + l4 * 8);
  }

  f32x4 acc[6];
  #pragma unroll
  for (int c = 0; c < 6; ++c) acc[c] = (f32x4){0.f, 0.f, 0.f, 0.f};
  float m_r[4] = {-INFINITY, -INFINITY, -INFINITY, -INFINITY};
  float l_r[4] = {0.f, 0.f, 0.f, 0.f};
  const float scale = 0.10206207261596576f;   // 1/sqrt(96)

  const int jmax = q0 + QB;
  for (int j0 = 0; j0 < jmax; j0 += KVB) {
    __syncthreads();
    {  // stage K tile: 32 rows x 96 bf16
      int row = t >> 2, seg = t & 3;
      const short* src = kb + ((size_t)(b * T_) + j0 + row) * H_ + seg * 24;
      short* dst = &ks[row][seg * 24];
      *reinterpret_cast<short8*>(dst)      = *reinterpret_cast<const short8*>(src);
      *reinterpret_cast<short8*>(dst + 8)  = *reinterpret_cast<const short8*>(src + 8);
      *reinterpret_cast<short8*>(dst + 16) = *reinterpret_cast<const short8*>(src + 16);
    }
    {  // stage V tile: 96 h x 32 keys (pre-transposed in global)
      #pragma unroll
      for (int i = 0; i < 3; ++i) {
        int c = t + i * 128;
        int h = c >> 2, k8 = c & 3;
        *reinterpret_cast<short8*>(&vs[h][k8 * 8]) =
            *reinterpret_cast<const short8*>(vtp + ((size_t)b * H_ + h) * T_ + j0 + k8 * 8);
      }
    }
    __syncthreads();

    f32x4 sfr[2];
    sfr[0] = (f32x4){0.f,0.f,0.f,0.f};
    sfr[1] = (f32x4){0.f,0.f,0.f,0.f};
    #pragma unroll
    for (int ct = 0; ct < 2; ++ct)
      #pragma unroll
      for (int f = 0; f < 3; ++f) {
        short8 kf = *reinterpret_cast<const short8*>(&ks[ct * 16 + l15][f * 32 + l4 * 8]);
        sfr[ct] = __builtin_amdgcn_mfma_f32_16x16x32_bf16(qf[f], kf, sfr[ct], 0, 0, 0);
      }

    const int qrow = q0 + w * 16 + l4 * 4;   // +reg
    float p0[4], p1[4], fsc[4];
    #pragma unroll
    for (int reg = 0; reg < 4; ++reg) {
      float s0 = sfr[0][reg] * scale;
      float s1 = sfr[1][reg] * scale;
      if (j0 + l15      > qrow + reg) s0 = -INFINITY;
      if (j0 + l15 + 16 > qrow + reg) s1 = -INFINITY;
      float tm = fmaxf(s0, s1);
      #pragma unroll
      for (int o = 1; o < 16; o <<= 1) tm = fmaxf(tm, __shfl_xor(tm, o));
      float Mnew = fmaxf(m_r[reg], tm);
      p0[reg] = __expf(s0 - Mnew);
      p1[reg] = __expf(s1 - Mnew);
      float psum = p0[reg] + p1[reg];
      #pragma unroll
      for (int o = 1; o < 16; o <<= 1) psum += __shfl_xor(psum, o);
      fsc[reg] = __expf(m_r[reg] - Mnew);
      m_r[reg] = Mnew;
      l_r[reg] = l_r[reg] * fsc[reg] + psum;
    }
    #pragma unroll
    for (int c = 0; c < 6; ++c)
      #pragma unroll
      for (int reg = 0; reg < 4; ++reg) acc[c][reg] *= fsc[reg];

    #pragma unroll
    for (int reg = 0; reg < 4; ++reg) {
      ps[w][l4 * 4 + reg][l15]      = f2bf(p0[reg]);
      ps[w][l4 * 4 + reg][l15 + 16] = f2bf(p1[reg]);
    }
    short8 pa = *reinterpret_cast<const short8*>(&ps[w][l15][l4 * 8]);

    #pragma unroll
    for (int c = 0; c < 6; ++c) {
      short8 vf = *reinterpret_cast<const short8*>(&vs[c * 16 + l15][l4 * 8]);
      acc[c] = __builtin_amdgcn_mfma_f32_16x16x32_bf16(pa, vf, acc[c], 0, 0, 0);
    }
  }

  float inv[4];
  #pragma unroll
  for (int reg = 0; reg < 4; ++reg) inv[reg] = 1.f / l_r[reg];
  #pragma unroll
  for (int c = 0; c < 6; ++c) {
    #pragma unroll
    for (int reg = 0; reg < 4; ++reg) {
      size_t row = (size_t)(b * T_) + q0 + w * 16 + l4 * 4 + reg;
      out[row * H_ + c * 16 + l15] = acc[c][reg] * inv[reg];
    }
  }
}

extern "C" void kernel_launch(void* const* d_in, const int* in_sizes, int n_in,
                              void* d_out, int out_size, void* d_ws, size_t ws_size,
                              hipStream_t stream) {
  const float* x  = (const float*)d_in[0];
  const float* Wq = (const float*)d_in[1];
  const float* Wk = (const float*)d_in[2];
  const float* Wv = (const float*)d_in[3];

  short* wt  = (short*)d_ws;                               // 442,368 B
  short* qb  = (short*)((char*)d_ws + 524288);             // 6,291,456 B
  short* kb  = qb + (size_t)M_ * H_;
  short* vtp = kb + (size_t)M_ * H_;                       // [B][96][T]
  float* outp = (float*)d_out;

  hipLaunchKernelGGL(wt_kernel, dim3((3*H_*D_ + 255)/256), dim3(256), 0, stream,
                     Wq, Wk, Wv, wt);
  hipLaunchKernelGGL(qkv_mfma_kernel, dim3(M_/BMP), dim3(256), 0, stream,
                     x, wt, qb, kb, vtp);
  hipLaunchKernelGGL(attn_mfma_kernel, dim3(T_/QB, B_), dim3(128), 0, stream,
                     qb, kb, vtp, outp);
}